// Round 10
// baseline (156.009 us; speedup 1.0000x reference)
//
#include <hip/hip_runtime.h>
#include <math.h>

#define EPS  1e-8f
#define C    768
#define HW   4096
#define NKB  24           // k-blocks of 32 (C/32)
#define NNB  12           // nbp2 chunks of 64 c (fast path)
#define NBN  32           // q-tiles of 128 (HW/128)
#define TAU  0.016f       // scaled-sim margin for fp32 recheck (~7 sigma of 1-pass err)
#define NCH_NEW 12        // c-tiles of 64 for transpose-gather
#define NCH_OLD 48        // c-chunks for fallback gather
#define NTT  (3 * (HW / 64) * (C / 64))   // 2304 transpose tiles (d,b,a)

typedef float  floatx4 __attribute__((ext_vector_type(4)));
typedef short  shortx8 __attribute__((ext_vector_type(8)));
typedef unsigned short ushort_t;
typedef unsigned int   uint_t;
typedef __attribute__((address_space(1))) uint_t as1_uint;
typedef __attribute__((address_space(3))) uint_t as3_uint;

__device__ __forceinline__ ushort_t f2bf(float v) {
    uint_t u = __float_as_uint(v);
    uint_t r = (u + 0x7FFFu + ((u >> 16) & 1u)) >> 16;   // RNE
    return (ushort_t)r;
}
__device__ __forceinline__ void async_cp16(const ushort_t* g, ushort_t* l) {
    __builtin_amdgcn_global_load_lds((const as1_uint*)g, (as3_uint*)l, 16, 0, 0);
}

// ---------------------------------------------------------------------------
// prep: pack-only. b -> Bh (bf16 swizzled granules) + nbp2; a -> Ah.
// Block (0,0) also zeroes the loss accumulator (out[0]).
// ---------------------------------------------------------------------------
__global__ __launch_bounds__(256) void prep_kernel(
    const float* __restrict__ a, const float* __restrict__ b,
    ushort_t* __restrict__ Ah, ushort_t* __restrict__ Bh,
    float* __restrict__ nbp2, float* __restrict__ out)
{
    __shared__ float tile[64][65];
    const int t = threadIdx.x;
    const int p0 = blockIdx.x * 64;
    const int c0 = blockIdx.y * 64;
    const int r16 = t >> 4;          // 0..15
    const int q4  = (t & 15) * 4;    // 0,4,...,60
    const int pl = t >> 2, g = t & 3;          // pack: thread -> (p-local, granule)
    const int pg = p0 + pl;
    const int sw = (pg >> 1) & 3;

    if (blockIdx.x == 0 && blockIdx.y == 0 && t == 0) out[0] = 0.f;

    // ---- b -> Bh + nbp2
#pragma unroll
    for (int pp = 0; pp < 4; ++pp) {
        int c = pp * 16 + r16;
        float4 v = *(const float4*)&b[(size_t)(c0 + c) * HW + p0 + q4];
        tile[c][q4]     = v.x; tile[c][q4 + 1] = v.y;
        tile[c][q4 + 2] = v.z; tile[c][q4 + 3] = v.w;
    }
    __syncthreads();
#pragma unroll
    for (int h = 0; h < 2; ++h) {
        const int kb = (c0 >> 5) + h;
        uint_t w[4];
#pragma unroll
        for (int u = 0; u < 4; ++u) {
            ushort_t lo = f2bf(tile[h * 32 + g * 8 + 2 * u][pl]);
            ushort_t hi = f2bf(tile[h * 32 + g * 8 + 2 * u + 1][pl]);
            w[u] = (uint_t)lo | ((uint_t)hi << 16);
        }
        uint4* oh = (uint4*)(Bh + ((size_t)kb * HW + pg) * 32);
        oh[g ^ sw] = make_uint4(w[0], w[1], w[2], w[3]);
    }
    if (t < 64) {
        float s = 0.f;
#pragma unroll
        for (int c = 0; c < 64; ++c) { float v = tile[c][t]; s += v * v; }
        nbp2[blockIdx.y * HW + p0 + t] = s;
    }
    __syncthreads();

    // ---- a -> Ah
#pragma unroll
    for (int pp = 0; pp < 4; ++pp) {
        int c = pp * 16 + r16;
        float4 v = *(const float4*)&a[(size_t)(c0 + c) * HW + p0 + q4];
        tile[c][q4]     = v.x; tile[c][q4 + 1] = v.y;
        tile[c][q4 + 2] = v.z; tile[c][q4 + 3] = v.w;
    }
    __syncthreads();
#pragma unroll
    for (int h = 0; h < 2; ++h) {
        const int kb = (c0 >> 5) + h;
        uint_t w[4];
#pragma unroll
        for (int u = 0; u < 4; ++u) {
            ushort_t lo = f2bf(tile[h * 32 + g * 8 + 2 * u][pl]);
            ushort_t hi = f2bf(tile[h * 32 + g * 8 + 2 * u + 1][pl]);
            w[u] = (uint_t)lo | ((uint_t)hi << 16);
        }
        uint4* oh = (uint4*)(Ah + ((size_t)kb * HW + pg) * 32);
        oh[g ^ sw] = make_uint4(w[0], w[1], w[2], w[3]);
    }
}

// ---------------------------------------------------------------------------
// MFMA GEMM (Ah*Bh): R7-proven config (128x128, BK=32, 4 waves, dbuf,
// XCD swizzle, top-2 epilogue) + transpose tail (d->dT, b->bT, a->aT
// overlapped with neighboring blocks' MFMA phases). UNCHANGED.
// ---------------------------------------------------------------------------
__global__ __launch_bounds__(256, 4) void gemm_mfma_kernel(
    const ushort_t* __restrict__ Ah, const ushort_t* __restrict__ Bh,
    const float* __restrict__ nbp2,
    const float* __restrict__ a, const float* __restrict__ b,
    const float* __restrict__ d,
    float* __restrict__ dT, float* __restrict__ bT,
    float* __restrict__ aT, int at_ok,
    float* __restrict__ pv1, int* __restrict__ pi1,
    float* __restrict__ pv2, int* __restrict__ pi2)
{
    __shared__ __align__(16) char smem[33280];
    ushort_t* sA0 = (ushort_t*)smem;              // 8 KB
    ushort_t* sB0 = (ushort_t*)(smem + 8192);     // 8 KB
    ushort_t* sA1 = (ushort_t*)(smem + 16384);    // 8 KB
    ushort_t* sB1 = (ushort_t*)(smem + 24576);    // 8 KB
    float*    nb_s = (float*)(smem + 32768);      // 512 B

    const int tid  = threadIdx.x;
    const int lane = tid & 63;
    const int wave = tid >> 6;
    const int wm = wave >> 1, wn = wave & 1;
    // XCD-aware bijective swizzle: grid 32x32 = 1024 = 8*128
    const int flat = blockIdx.y * (HW / 128) + blockIdx.x;
    const int orig = (flat & 7) * 128 + (flat >> 3);
    const int bm = orig >> 5, bn = orig & 31;
    const int l15 = lane & 15, l4 = lane >> 4;
    const int swz = (l15 >> 1) & 3;

    floatx4 acc[4][4];
#pragma unroll
    for (int i = 0; i < 4; ++i)
#pragma unroll
        for (int j = 0; j < 4; ++j) acc[i][j] = (floatx4){0.f, 0.f, 0.f, 0.f};

    auto stage = [&](int kb, ushort_t* dA, ushort_t* dB) {
        const size_t aoff = (size_t)(kb * HW + bm * 128) * 32 + tid * 8;
        const size_t boff = (size_t)(kb * HW + bn * 128) * 32 + tid * 8;
        async_cp16(Ah + aoff,        dA + tid * 8);
        async_cp16(Ah + aoff + 2048, dA + tid * 8 + 2048);
        async_cp16(Bh + boff,        dB + tid * 8);
        async_cp16(Bh + boff + 2048, dB + tid * 8 + 2048);
    };
    auto compute = [&](const ushort_t* pA, const ushort_t* pB) {
        shortx8 af[4], bf_[4];
#pragma unroll
        for (int i = 0; i < 4; ++i)
            af[i] = *(const shortx8*)&pA[((wm * 4 + i) * 16 + l15) * 32 + ((l4 ^ swz) * 8)];
#pragma unroll
        for (int j = 0; j < 4; ++j)
            bf_[j] = *(const shortx8*)&pB[((wn * 4 + j) * 16 + l15) * 32 + ((l4 ^ swz) * 8)];
#pragma unroll
        for (int i = 0; i < 4; ++i)
#pragma unroll
            for (int j = 0; j < 4; ++j)
                acc[i][j] = __builtin_amdgcn_mfma_f32_16x16x32_bf16(af[i], bf_[j], acc[i][j], 0, 0, 0);
    };

    // prologue: stage kb=0 into buf0; its latency overlaps the nb_s work
    stage(0, sA0, sB0);
    if (tid < 128) {
        float s = 0.f;
        int q = bn * 128 + tid;
#pragma unroll
        for (int ch = 0; ch < NNB; ++ch) s += nbp2[ch * HW + q];
        nb_s[tid] = 1.0f / (sqrtf(s + EPS) + EPS);
    }
    __syncthreads();

    // main loop, manually unrolled x2 so buffer choice is compile-time
    for (int kb = 0; kb < NKB; kb += 2) {
        stage(kb + 1, sA1, sB1);          // kb+1 <= 23 always valid (NKB even)
        compute(sA0, sB0);
        __syncthreads();
        if (kb + 2 < NKB) stage(kb + 2, sA0, sB0);
        compute(sA1, sB1);
        __syncthreads();
    }

    float rnb[4];
#pragma unroll
    for (int j = 0; j < 4; ++j)
        rnb[j] = nb_s[wn * 64 + j * 16 + l15];

    float* lv1 = (float*)smem;
    int*   li1 = (int*)(smem + 1024);
    float* lv2 = (float*)(smem + 2048);
    int*   li2 = (int*)(smem + 3072);

#pragma unroll
    for (int i = 0; i < 4; ++i) {
#pragma unroll
        for (int r = 0; r < 4; ++r) {
            float v1 = -INFINITY, v2 = -INFINITY; int i1 = 0, i2 = 0;
#pragma unroll
            for (int j = 0; j < 4; ++j) {
                float sv = acc[i][j][r] * rnb[j];
                int q = bn * 128 + wn * 64 + j * 16 + l15;
                if (sv > v1) { v2 = v1; i2 = i1; v1 = sv; i1 = q; }
                else if (sv > v2) { v2 = sv; i2 = q; }
            }
#pragma unroll
            for (int m = 1; m < 16; m <<= 1) {
                float ov1 = __shfl_xor(v1, m, 64);
                int   oi1 = __shfl_xor(i1, m, 64);
                float ov2 = __shfl_xor(v2, m, 64);
                int   oi2 = __shfl_xor(i2, m, 64);
                if (ov1 > v1 || (ov1 == v1 && oi1 < i1)) {
                    if (v1 > ov2 || (v1 == ov2 && i1 < oi2)) { v2 = v1; i2 = i1; }
                    else { v2 = ov2; i2 = oi2; }
                    v1 = ov1; i1 = oi1;
                } else if (ov1 > v2 || (ov1 == v2 && oi1 < i2)) {
                    v2 = ov1; i2 = oi1;
                }
            }
            if (l15 == 0) {
                int pl = wm * 64 + i * 16 + l4 * 4 + r;
                lv1[pl * 2 + wn] = v1; li1[pl * 2 + wn] = i1;
                lv2[pl * 2 + wn] = v2; li2[pl * 2 + wn] = i2;
            }
        }
    }
    __syncthreads();
    if (tid < 128) {
        float v1 = lv1[tid * 2],     v2 = lv2[tid * 2];
        int   i1 = li1[tid * 2],     i2 = li2[tid * 2];
        float w1 = lv1[tid * 2 + 1], w2 = lv2[tid * 2 + 1];
        int   j1 = li1[tid * 2 + 1], j2 = li2[tid * 2 + 1];
        if (w1 > v1 || (w1 == v1 && j1 < i1)) {
            if (v1 > w2 || (v1 == w2 && i1 < j2)) { v2 = v1; i2 = i1; }
            else { v2 = w2; i2 = j2; }
            v1 = w1; i1 = j1;
        } else if (w1 > v2 || (w1 == v2 && j1 < i2)) {
            v2 = w1; i2 = j1;
        }
        int p = bm * 128 + tid;
        pv1[p * NBN + bn] = v1; pi1[p * NBN + bn] = i1;
        pv2[p * NBN + bn] = v2; pi2[p * NBN + bn] = i2;
    }

    // ---- transpose tail: 2-3 64x64 tiles per block (d->dT, b->bT, a->aT)
    __syncthreads();                       // epilogue LDS readers done
    {
        float (*tile)[65] = (float (*)[65])smem;     // 16640 B <= 33280
        const int r16 = tid >> 4;
        const int q4  = (tid & 15) * 4;
        const int flatb = blockIdx.y * (HW / 128) + blockIdx.x;  // 0..1023
        for (int tt = flatb; tt < NTT; tt += 1024) {
            const int which = tt / 768;              // 0=d, 1=b, 2=a
            const int idx = tt - which * 768;
            if (which == 2 && !at_ok) break;         // aT tiles are always last
            const float* src = (which == 0) ? d : ((which == 1) ? b : a);
            float*       dst = (which == 0) ? dT : ((which == 1) ? bT : aT);
            const int tp0 = (idx & 63) * 64;
            const int tc0 = (idx >> 6) * 64;
#pragma unroll
            for (int pp = 0; pp < 4; ++pp) {
                int c = pp * 16 + r16;
                float4 v = *(const float4*)&src[(size_t)(tc0 + c) * HW + tp0 + q4];
                tile[c][q4]     = v.x; tile[c][q4 + 1] = v.y;
                tile[c][q4 + 2] = v.z; tile[c][q4 + 3] = v.w;
            }
            __syncthreads();
#pragma unroll
            for (int pp = 0; pp < 4; ++pp) {
                int p = pp * 16 + r16;
                float4 v;
                v.x = tile[q4][p];     v.y = tile[q4 + 1][p];
                v.z = tile[q4 + 2][p]; v.w = tile[q4 + 3][p];
                *(float4*)&dst[(size_t)(tp0 + p) * C + tc0 + q4] = v;
            }
            __syncthreads();
        }
    }
}

// ---------------------------------------------------------------------------
// reduce+recheck: 4 rows per block (1 per wave). Top-2 merge over 32 tiles;
// flagged rows get cooperative fp32 recheck of TAU-surviving candidates.
// NEW (at_ok): after zb[p] is final, the wave computes that row's cos-loss
// contribution directly from aT[p] / dT[zb[p]] (12 floats/lane, coalesced)
// via butterfly reduce -- one atomicAdd(out) per block. This removes the
// loss work (a-reads, partials, finalize launch) from the gather stage.
// ---------------------------------------------------------------------------
__global__ __launch_bounds__(256) void reduce_recheck_kernel(
    const float* __restrict__ a, const float* __restrict__ b,
    const float* __restrict__ bT, int bt_ok,
    const float* __restrict__ aT, int at_ok,
    const float* __restrict__ dT,
    const float* __restrict__ pv1, const int* __restrict__ pi1,
    const float* __restrict__ pv2, const int* __restrict__ pi2,
    int* __restrict__ zb, float* __restrict__ out_zbest,
    float* __restrict__ out)
{
    const int wave = threadIdx.x >> 6, lane = threadIdx.x & 63;
    const int p = blockIdx.x * 4 + wave;
    const int tq = lane & 31;
    __shared__ float cshare[4];

    float v1, v2, candv; int i1, cand;
    if (lane < 32) {
        v1 = pv1[p * NBN + tq]; i1 = pi1[p * NBN + tq]; v2 = pv2[p * NBN + tq];
        cand = i1; candv = v1;
    } else {
        v1 = -INFINITY; v2 = -INFINITY; i1 = 0x7fffffff;
        cand = pi2[p * NBN + tq];
        candv = pv2[p * NBN + tq];
    }
#pragma unroll
    for (int m = 1; m < 32; m <<= 1) {
        float ov1 = __shfl_xor(v1, m, 64);
        int   oi1 = __shfl_xor(i1, m, 64);
        float ov2 = __shfl_xor(v2, m, 64);
        if (ov1 > v1 || (ov1 == v1 && oi1 < i1)) {
            v2 = fmaxf(v1, ov2); v1 = ov1; i1 = oi1;
        } else {
            v2 = fmaxf(v2, ov1);
        }
    }
    v1 = __shfl(v1, 0, 64); v2 = __shfl(v2, 0, 64); i1 = __shfl(i1, 0, 64);

    int qfinal;
    if (v1 - v2 >= TAU) {
        qfinal = i1;
    } else if (at_ok) {
        // cooperative recheck over TAU-surviving candidates
        const bool active = candv >= v1 - TAU;
        unsigned long long mset = __ballot(active);
        const float* ar = aT + (size_t)p * C + lane * 12;
        float4 a0 = *(const float4*)ar;
        float4 a1 = *(const float4*)(ar + 4);
        float4 a2v = *(const float4*)(ar + 8);
        float bests = -INFINITY; int bestq = 0x7fffffff;
        while (mset) {
            const int src = __ffsll(mset) - 1;
            mset &= mset - 1;
            const int qc = __shfl(cand, src, 64);
            const float* br = bT + (size_t)qc * C + lane * 12;
            float4 b0 = *(const float4*)br;
            float4 b1 = *(const float4*)(br + 4);
            float4 b2v = *(const float4*)(br + 8);
            float dot = a0.x * b0.x + a0.y * b0.y + a0.z * b0.z + a0.w * b0.w
                      + a1.x * b1.x + a1.y * b1.y + a1.z * b1.z + a1.w * b1.w
                      + a2v.x * b2v.x + a2v.y * b2v.y + a2v.z * b2v.z + a2v.w * b2v.w;
            float bb  = b0.x * b0.x + b0.y * b0.y + b0.z * b0.z + b0.w * b0.w
                      + b1.x * b1.x + b1.y * b1.y + b1.z * b1.z + b1.w * b1.w
                      + b2v.x * b2v.x + b2v.y * b2v.y + b2v.z * b2v.z + b2v.w * b2v.w;
#pragma unroll
            for (int m = 1; m < 64; m <<= 1) {
                dot += __shfl_xor(dot, m, 64);
                bb  += __shfl_xor(bb, m, 64);
            }
            const float s = dot / (sqrtf(bb + EPS) + EPS);
            if (s > bests || (s == bests && qc < bestq)) { bests = s; bestq = qc; }
        }
        qfinal = bestq;
    } else {
        // per-lane fallback recheck (no aT)
        const bool active = candv >= v1 - TAU;
        int q = cand;
        float dot = 0.f, b2 = 0.f;
        if (active) {
            if (bt_ok) {
                const float* br = bT + (size_t)q * C;
                const float* ap = a + p;
#pragma unroll 4
                for (int c = 0; c < C; c += 4) {
                    float4 bv = *(const float4*)(br + c);
                    dot += ap[(size_t)c * HW] * bv.x + ap[(size_t)(c + 1) * HW] * bv.y
                         + ap[(size_t)(c + 2) * HW] * bv.z + ap[(size_t)(c + 3) * HW] * bv.w;
                    b2  += bv.x * bv.x + bv.y * bv.y + bv.z * bv.z + bv.w * bv.w;
                }
            } else {
#pragma unroll 8
                for (int c = 0; c < C; ++c) {
                    float av = a[c * HW + p];
                    float bv = b[c * HW + q];
                    dot += av * bv; b2 += bv * bv;
                }
            }
        }
        float s = active ? (dot / (sqrtf(b2 + EPS) + EPS)) : -INFINITY;
#pragma unroll
        for (int m = 1; m < 64; m <<= 1) {
            float os = __shfl_xor(s, m, 64);
            int   oq = __shfl_xor(q, m, 64);
            if (os > s || (os == s && oq < q)) { s = os; q = oq; }
        }
        qfinal = q;   // uniform: full 64-lane butterfly
    }
    if (lane == 0) { zb[p] = qfinal; out_zbest[p] = (float)qfinal; }

    // ---- fused per-row cos-loss (at_ok path only)
    if (at_ok) {
        const float* ar = aT + (size_t)p * C + lane * 12;
        const float* dr = dT + (size_t)qfinal * C + lane * 12;
        float4 x0 = *(const float4*)ar;
        float4 x1 = *(const float4*)(ar + 4);
        float4 x2 = *(const float4*)(ar + 8);
        float4 y0 = *(const float4*)dr;
        float4 y1 = *(const float4*)(dr + 4);
        float4 y2 = *(const float4*)(dr + 8);
        float dotv = x0.x * y0.x + x0.y * y0.y + x0.z * y0.z + x0.w * y0.w
                   + x1.x * y1.x + x1.y * y1.y + x1.z * y1.z + x1.w * y1.w
                   + x2.x * y2.x + x2.y * y2.y + x2.z * y2.z + x2.w * y2.w;
        float aa   = x0.x * x0.x + x0.y * x0.y + x0.z * x0.z + x0.w * x0.w
                   + x1.x * x1.x + x1.y * x1.y + x1.z * x1.z + x1.w * x1.w
                   + x2.x * x2.x + x2.y * x2.y + x2.z * x2.z + x2.w * x2.w;
        float tt   = y0.x * y0.x + y0.y * y0.y + y0.z * y0.z + y0.w * y0.w
                   + y1.x * y1.x + y1.y * y1.y + y1.z * y1.z + y1.w * y1.w
                   + y2.x * y2.x + y2.y * y2.y + y2.z * y2.z + y2.w * y2.w;
#pragma unroll
        for (int m = 1; m < 64; m <<= 1) {
            dotv += __shfl_xor(dotv, m, 64);
            aa   += __shfl_xor(aa, m, 64);
            tt   += __shfl_xor(tt, m, 64);
        }
        if (lane == 0)
            cshare[wave] = 1.f - dotv / ((sqrtf(aa) + EPS) * (sqrtf(tt) + EPS));
    }
    __syncthreads();
    if (threadIdx.x == 0 && at_ok)
        atomicAdd(out, (cshare[0] + cshare[1] + cshare[2] + cshare[3]) * (1.0f / HW));
}

// ---------------------------------------------------------------------------
// transpose-gather z_new (32p x 64c tiles, R7-proven config). When
// do_partials==0 (at_ok fast path) this is a pure transpose-scatter:
// no a-reads, no partials, no second reduce phase.
// ---------------------------------------------------------------------------
__global__ __launch_bounds__(256) void gather_loss_kernel(
    const float* __restrict__ a, const float* __restrict__ dT,
    const int* __restrict__ zb, float* __restrict__ out,
    float* __restrict__ pdot, float* __restrict__ pa2, float* __restrict__ pt2,
    int do_partials)
{
    __shared__ float tile[32][65];
    __shared__ int qs[32];
    const int t = threadIdx.x;
    const int p0 = blockIdx.x * 32;
    const int c0 = blockIdx.y * 64;
    if (t < 32) qs[t] = zb[p0 + t];
    __syncthreads();

    {
        const int pl = t >> 3, sub = t & 7;          // 32 rows x 8 threads
        const float* src = dT + (size_t)qs[pl] * C + c0 + sub * 8;
        float4 v0 = *(const float4*)(src);
        float4 v1 = *(const float4*)(src + 4);
        float* dst = &tile[pl][sub * 8];
        dst[0] = v0.x; dst[1] = v0.y; dst[2] = v0.z; dst[3] = v0.w;
        dst[4] = v1.x; dst[5] = v1.y; dst[6] = v1.z; dst[7] = v1.w;
    }
    __syncthreads();

    const int p = t & 31, cg = t >> 5;               // 8 groups x 8 c
    if (!do_partials) {
        // pure transpose-scatter of z_new
#pragma unroll
        for (int i = 0; i < 8; ++i) {
            int cc = cg * 8 + i;
            out[1 + (size_t)(c0 + cc) * HW + p0 + p] = tile[p][cc];
        }
        return;
    }

    float dot = 0.f, a2 = 0.f, t2 = 0.f;
#pragma unroll
    for (int i = 0; i < 8; ++i) {
        int cc = cg * 8 + i;
        float tv = tile[p][cc];
        float av = a[(size_t)(c0 + cc) * HW + p0 + p];
        out[1 + (size_t)(c0 + cc) * HW + p0 + p] = tv;
        dot += av * tv; a2 += av * av; t2 += tv * tv;
    }
    __shared__ float r1[256], r2[256], r3[256];
    r1[t] = dot; r2[t] = a2; r3[t] = t2;
    __syncthreads();
    if (t < 32) {
        float fd = 0.f, fa = 0.f, ft = 0.f;
#pragma unroll
        for (int g = 0; g < 8; ++g) {
            fd += r1[t + g * 32];
            fa += r2[t + g * 32];
            ft += r3[t + g * 32];
        }
        pdot[blockIdx.y * HW + p0 + t] = fd;
        pa2[blockIdx.y * HW + p0 + t]  = fa;
        pt2[blockIdx.y * HW + p0 + t]  = ft;
    }
}

// loss finalize (used only when at_ok == 0)
__global__ __launch_bounds__(256) void loss_finalize_kernel(
    const float* __restrict__ pdot, const float* __restrict__ pa2,
    const float* __restrict__ pt2, float* __restrict__ out, int nch)
{
    int p4 = (blockIdx.x * 256 + threadIdx.x) * 4;
    float d0 = 0.f, d1 = 0.f, d2 = 0.f, d3 = 0.f;
    float a0 = 0.f, a1 = 0.f, a2 = 0.f, a3 = 0.f;
    float t0 = 0.f, t1 = 0.f, t2 = 0.f, t3 = 0.f;
    for (int ch = 0; ch < nch; ++ch) {
        float4 dv = *(const float4*)&pdot[(size_t)ch * HW + p4];
        float4 av = *(const float4*)&pa2[(size_t)ch * HW + p4];
        float4 tv = *(const float4*)&pt2[(size_t)ch * HW + p4];
        d0 += dv.x; d1 += dv.y; d2 += dv.z; d3 += dv.w;
        a0 += av.x; a1 += av.y; a2 += av.z; a3 += av.w;
        t0 += tv.x; t1 += tv.y; t2 += tv.z; t3 += tv.w;
    }
    float contrib =
        (1.f - d0 / ((sqrtf(a0) + EPS) * (sqrtf(t0) + EPS))) +
        (1.f - d1 / ((sqrtf(a1) + EPS) * (sqrtf(t1) + EPS))) +
        (1.f - d2 / ((sqrtf(a2) + EPS) * (sqrtf(t2) + EPS))) +
        (1.f - d3 / ((sqrtf(a3) + EPS) * (sqrtf(t3) + EPS)));
    __shared__ float red[256];
    red[threadIdx.x] = contrib;
    __syncthreads();
    for (int s = 128; s > 0; s >>= 1) {
        if (threadIdx.x < s) red[threadIdx.x] += red[threadIdx.x + s];
        __syncthreads();
    }
    if (threadIdx.x == 0) atomicAdd(out, red[0] * (1.0f / HW));
}

// ---------------------------------------------------------------------------
// fp32 fallback path (only if workspace is unexpectedly small)
// ---------------------------------------------------------------------------
__global__ __launch_bounds__(256) void bnorm_partial_fb_kernel(
    const float* __restrict__ b, float* __restrict__ nbp)
{
    int q = blockIdx.x * 256 + threadIdx.x;
    int c0 = blockIdx.y * 32;
    float s = 0.f;
#pragma unroll 8
    for (int c = c0; c < c0 + 32; ++c) { float v = b[c * HW + q]; s += v * v; }
    nbp[blockIdx.y * HW + q] = s;
}

__global__ __launch_bounds__(256) void bnorm_finalize_fb_kernel(
    const float* __restrict__ nbp, float* __restrict__ nb)
{
    int q = blockIdx.x * 256 + threadIdx.x;
    float s = 0.f;
#pragma unroll
    for (int ch = 0; ch < NKB; ++ch) s += nbp[ch * HW + q];
    nb[q] = sqrtf(s + EPS) + EPS;
}

__global__ __launch_bounds__(256) void gemm_argmax_fb_kernel(
    const float* __restrict__ A, const float* __restrict__ B,
    const float* __restrict__ nb,
    float* __restrict__ pval, int* __restrict__ pidx)
{
    __shared__ __align__(16) char smem[16384];
    float (*As)[128] = (float (*)[128])smem;
    float (*Bs)[128] = (float (*)[128])(smem + 4096);
    const int m0 = blockIdx.x * 128, q0 = blockIdx.y * 128;
    const int tid = threadIdx.x;
    const int tx = tid & 15, ty = tid >> 4;
    const int lr = tid >> 5, lc = (tid & 31) * 4;
    float acc[8][8] = {};
    for (int k0 = 0; k0 < C; k0 += 8) {
        *(float4*)&As[lr][lc] = *(const float4*)&A[(k0 + lr) * HW + m0 + lc];
        *(float4*)&Bs[lr][lc] = *(const float4*)&B[(k0 + lr) * HW + q0 + lc];
        __syncthreads();
#pragma unroll
        for (int kk = 0; kk < 8; ++kk) {
            float a8[8], b8[8];
            *(float4*)&a8[0] = *(float4*)&As[kk][ty * 8];
            *(float4*)&a8[4] = *(float4*)&As[kk][ty * 8 + 4];
            *(float4*)&b8[0] = *(float4*)&Bs[kk][tx * 8];
            *(float4*)&b8[4] = *(float4*)&Bs[kk][tx * 8 + 4];
#pragma unroll
            for (int i = 0; i < 8; ++i)
#pragma unroll
                for (int j = 0; j < 8; ++j) acc[i][j] += a8[i] * b8[j];
        }
        __syncthreads();
    }
    float nbv[8];
#pragma unroll
    for (int j = 0; j < 8; ++j) nbv[j] = nb[q0 + tx * 8 + j];
    float (*rv)[16] = (float (*)[16])smem;
    int   (*ri)[16] = (int   (*)[16])(smem + 8192);
#pragma unroll
    for (int i = 0; i < 8; ++i) {
        float bv = -INFINITY; int bi = 0;
#pragma unroll
        for (int j = 0; j < 8; ++j) {
            float s = acc[i][j] / nbv[j];
            int q = q0 + tx * 8 + j;
            if (s > bv) { bv = s; bi = q; }
        }
        rv[ty * 8 + i][tx] = bv;
        ri[ty * 8 + i][tx] = bi;
    }
    __syncthreads();
    if (tid < 128) {
        float bv = rv[tid][0]; int bi = ri[tid][0];
#pragma unroll
        for (int t = 1; t < 16; ++t) {
            float v = rv[tid][t]; int ii = ri[tid][t];
            if (v > bv || (v == bv && ii < bi)) { bv = v; bi = ii; }
        }
        pval[(m0 + tid) * NBN + blockIdx.y] = bv;
        pidx[(m0 + tid) * NBN + blockIdx.y] = bi;
    }
}

__global__ __launch_bounds__(256) void reduce_fb_kernel(
    const float* __restrict__ pval, const int* __restrict__ pidx,
    int* __restrict__ zb, float* __restrict__ out_zbest)
{
    int p = blockIdx.x * 256 + threadIdx.x;
    float bv = pval[p * NBN]; int bi = pidx[p * NBN];
#pragma unroll 8
    for (int t = 1; t < NBN; ++t) {
        float v = pval[p * NBN + t]; int ii = pidx[p * NBN + t];
        if (v > bv || (v == bv && ii < bi)) { bv = v; bi = ii; }
    }
    zb[p] = bi;
    out_zbest[p] = (float)bi;
}

__global__ __launch_bounds__(256) void gather_partial_kernel(
    const float* __restrict__ a, const float* __restrict__ d,
    const int* __restrict__ zb, float* __restrict__ out,
    float* __restrict__ pdot, float* __restrict__ pa2, float* __restrict__ pt2)
{
    int p = blockIdx.x * 256 + threadIdx.x;
    int ch = blockIdx.y;
    int c0 = ch * (C / NCH_OLD);
    int q = zb[p];
    float dot = 0.f, a2 = 0.f, t2 = 0.f;
#pragma unroll
    for (int c = c0; c < c0 + C / NCH_OLD; ++c) {
        float av = a[c * HW + p];
        float tv = d[c * HW + q];
        dot += av * tv; a2 += av * av; t2 += tv * tv;
        out[1 + c * HW + p] = tv;
    }
    pdot[ch * HW + p] = dot;
    pa2[ch * HW + p] = a2;
    pt2[ch * HW + p] = t2;
}

extern "C" void kernel_launch(void* const* d_in, const int* in_sizes, int n_in,
                              void* d_out, int out_size, void* d_ws, size_t ws_size,
                              hipStream_t stream) {
    const float* a = (const float*)d_in[0];
    const float* b = (const float*)d_in[1];
    const float* d = (const float*)d_in[2];
    float* out = (float*)d_out;
    float* out_zbest = out + 1 + (size_t)C * HW;

    char* ws = (char*)d_ws;
    size_t off = 0;
    auto alloc = [&](size_t bytes) { void* p = ws + off; off = (off + bytes + 255) & ~(size_t)255; return p; };

    const size_t PACK = (size_t)C * HW * 2;  // 6.29 MB
    ushort_t* Ah = (ushort_t*)alloc(PACK);
    ushort_t* Bh = (ushort_t*)alloc(PACK);
    float* nbp = (float*)alloc((size_t)NKB * HW * 4);
    float* pv1 = (float*)alloc((size_t)HW * NBN * 4);
    int*   pi1 = (int*)alloc((size_t)HW * NBN * 4);
    float* pv2 = (float*)alloc((size_t)HW * NBN * 4);
    int*   pi2 = (int*)alloc((size_t)HW * NBN * 4);
    int*   zb  = (int*)alloc(HW * 4);
    float* pdot = (float*)alloc((size_t)NCH_NEW * HW * 4);
    float* pa2  = (float*)alloc((size_t)NCH_NEW * HW * 4);
    float* pt2  = (float*)alloc((size_t)NCH_NEW * HW * 4);
    float* dT  = (float*)alloc((size_t)C * HW * 4);   // 12.6 MB
    float* bT  = (float*)alloc((size_t)C * HW * 4);   // 12.6 MB
    bool fast = off <= ws_size;                       // ~41 MB
    float* aT  = (float*)alloc((size_t)C * HW * 4);   // 12.6 MB (optional)
    int at_ok = (off <= ws_size) ? 1 : 0;             // ~54 MB

    if (fast) {
        prep_kernel<<<dim3(HW / 64, C / 64), 256, 0, stream>>>(
            a, b, Ah, Bh, nbp, out);
        gemm_mfma_kernel<<<dim3(HW / 128, HW / 128), 256, 0, stream>>>(
            Ah, Bh, nbp, a, b, d, dT, bT, aT, at_ok, pv1, pi1, pv2, pi2);
        reduce_recheck_kernel<<<HW / 4, 256, 0, stream>>>(
            a, b, bT, 1, aT, at_ok, dT, pv1, pi1, pv2, pi2, zb, out_zbest, out);
        gather_loss_kernel<<<dim3(HW / 32, NCH_NEW), 256, 0, stream>>>(
            a, dT, zb, out, pdot, pa2, pt2, at_ok ? 0 : 1);
        if (!at_ok)
            loss_finalize_kernel<<<HW / 1024, 256, 0, stream>>>(pdot, pa2, pt2, out, NCH_NEW);
    } else {
        // compact fp32 fallback
        off = 0;
        float* nb = (float*)alloc(HW * 4);
        nbp = (float*)alloc((size_t)NKB * HW * 4);
        pv1 = (float*)alloc((size_t)HW * NBN * 4);
        pi1 = (int*)alloc((size_t)HW * NBN * 4);
        zb  = (int*)alloc(HW * 4);
        float* pdot2 = (float*)alloc((size_t)NCH_OLD * HW * 4);
        float* pa22  = (float*)alloc((size_t)NCH_OLD * HW * 4);
        float* pt22  = (float*)alloc((size_t)NCH_OLD * HW * 4);
        hipMemsetAsync(d_out, 0, sizeof(float), stream);
        bnorm_partial_fb_kernel<<<dim3(HW / 256, NKB), 256, 0, stream>>>(b, nbp);
        bnorm_finalize_fb_kernel<<<HW / 256, 256, 0, stream>>>(nbp, nb);
        gemm_argmax_fb_kernel<<<dim3(HW / 128, HW / 128), 256, 0, stream>>>(a, b, nb, pv1, pi1);
        reduce_fb_kernel<<<HW / 256, 256, 0, stream>>>(pv1, pi1, zb, out_zbest);
        gather_partial_kernel<<<dim3(HW / 256, NCH_OLD), 256, 0, stream>>>(
            a, d, zb, out, pdot2, pa22, pt22);
        loss_finalize_kernel<<<HW / 1024, 256, 0, stream>>>(pdot2, pa22, pt22, out, NCH_OLD);
    }
}

// Round 11
// 148.414 us; speedup vs baseline: 1.0512x; 1.0512x over previous
//
#include <hip/hip_runtime.h>
#include <math.h>

#define EPS  1e-8f
#define C    768
#define HW   4096
#define NKB  24           // k-blocks of 32 (C/32)
#define NNB  12           // nbp2 chunks of 64 c (fast path)
#define NBN  32           // q-tiles of 128 (HW/128)
#define TAU  0.016f       // scaled-sim margin for fp32 recheck (~7 sigma of 1-pass err)
#define NCH_NEW 12        // c-tiles of 64 for transpose-gather
#define NCH_OLD 48        // c-chunks for fallback gather
#define NTT  (3 * (HW / 64) * (C / 64))   // 2304 transpose tiles (d,b,a)

typedef float  floatx4 __attribute__((ext_vector_type(4)));
typedef short  shortx8 __attribute__((ext_vector_type(8)));
typedef unsigned short ushort_t;
typedef unsigned int   uint_t;
typedef __attribute__((address_space(1))) uint_t as1_uint;
typedef __attribute__((address_space(3))) uint_t as3_uint;

__device__ __forceinline__ ushort_t f2bf(float v) {
    uint_t u = __float_as_uint(v);
    uint_t r = (u + 0x7FFFu + ((u >> 16) & 1u)) >> 16;   // RNE
    return (ushort_t)r;
}
__device__ __forceinline__ void async_cp16(const ushort_t* g, ushort_t* l) {
    __builtin_amdgcn_global_load_lds((const as1_uint*)g, (as3_uint*)l, 16, 0, 0);
}

// ---------------------------------------------------------------------------
// prep: pack-only. b -> Bh (bf16 swizzled granules) + nbp2; a -> Ah.
// NEW: two LDS tiles, all 8 float4 loads issued up-front, ONE barrier
// (was 3) -- 2x memory-level parallelism on the load phase.
// Block (0,0) also zeroes the loss accumulator (out[0]).
// ---------------------------------------------------------------------------
__global__ __launch_bounds__(256) void prep_kernel(
    const float* __restrict__ a, const float* __restrict__ b,
    ushort_t* __restrict__ Ah, ushort_t* __restrict__ Bh,
    float* __restrict__ nbp2, float* __restrict__ out)
{
    __shared__ float tileB[64][65];
    __shared__ float tileA[64][65];
    const int t = threadIdx.x;
    const int p0 = blockIdx.x * 64;
    const int c0 = blockIdx.y * 64;
    const int r16 = t >> 4;          // 0..15
    const int q4  = (t & 15) * 4;    // 0,4,...,60
    const int pl = t >> 2, g = t & 3;          // pack: thread -> (p-local, granule)
    const int pg = p0 + pl;
    const int sw = (pg >> 1) & 3;

    if (blockIdx.x == 0 && blockIdx.y == 0 && t == 0) out[0] = 0.f;

    // ---- load b and a tiles (8 outstanding float4 loads per thread)
#pragma unroll
    for (int pp = 0; pp < 4; ++pp) {
        int c = pp * 16 + r16;
        float4 vb = *(const float4*)&b[(size_t)(c0 + c) * HW + p0 + q4];
        float4 va = *(const float4*)&a[(size_t)(c0 + c) * HW + p0 + q4];
        tileB[c][q4]     = vb.x; tileB[c][q4 + 1] = vb.y;
        tileB[c][q4 + 2] = vb.z; tileB[c][q4 + 3] = vb.w;
        tileA[c][q4]     = va.x; tileA[c][q4 + 1] = va.y;
        tileA[c][q4 + 2] = va.z; tileA[c][q4 + 3] = va.w;
    }
    __syncthreads();

    // ---- b -> Bh + nbp2
#pragma unroll
    for (int h = 0; h < 2; ++h) {
        const int kb = (c0 >> 5) + h;
        uint_t w[4];
#pragma unroll
        for (int u = 0; u < 4; ++u) {
            ushort_t lo = f2bf(tileB[h * 32 + g * 8 + 2 * u][pl]);
            ushort_t hi = f2bf(tileB[h * 32 + g * 8 + 2 * u + 1][pl]);
            w[u] = (uint_t)lo | ((uint_t)hi << 16);
        }
        uint4* oh = (uint4*)(Bh + ((size_t)kb * HW + pg) * 32);
        oh[g ^ sw] = make_uint4(w[0], w[1], w[2], w[3]);
    }
    if (t < 64) {
        float s = 0.f;
#pragma unroll
        for (int c = 0; c < 64; ++c) { float v = tileB[c][t]; s += v * v; }
        nbp2[blockIdx.y * HW + p0 + t] = s;
    }

    // ---- a -> Ah (tileA untouched by anyone else; no barrier needed)
#pragma unroll
    for (int h = 0; h < 2; ++h) {
        const int kb = (c0 >> 5) + h;
        uint_t w[4];
#pragma unroll
        for (int u = 0; u < 4; ++u) {
            ushort_t lo = f2bf(tileA[h * 32 + g * 8 + 2 * u][pl]);
            ushort_t hi = f2bf(tileA[h * 32 + g * 8 + 2 * u + 1][pl]);
            w[u] = (uint_t)lo | ((uint_t)hi << 16);
        }
        uint4* oh = (uint4*)(Ah + ((size_t)kb * HW + pg) * 32);
        oh[g ^ sw] = make_uint4(w[0], w[1], w[2], w[3]);
    }
}

// ---------------------------------------------------------------------------
// MFMA GEMM (Ah*Bh): R7-proven config (128x128, BK=32, 4 waves, dbuf,
// XCD swizzle, top-2 epilogue) + transpose tail (d->dT, b->bT, a->aT
// overlapped with neighboring blocks' MFMA phases). UNCHANGED.
// ---------------------------------------------------------------------------
__global__ __launch_bounds__(256, 4) void gemm_mfma_kernel(
    const ushort_t* __restrict__ Ah, const ushort_t* __restrict__ Bh,
    const float* __restrict__ nbp2,
    const float* __restrict__ a, const float* __restrict__ b,
    const float* __restrict__ d,
    float* __restrict__ dT, float* __restrict__ bT,
    float* __restrict__ aT, int at_ok,
    float* __restrict__ pv1, int* __restrict__ pi1,
    float* __restrict__ pv2, int* __restrict__ pi2)
{
    __shared__ __align__(16) char smem[33280];
    ushort_t* sA0 = (ushort_t*)smem;              // 8 KB
    ushort_t* sB0 = (ushort_t*)(smem + 8192);     // 8 KB
    ushort_t* sA1 = (ushort_t*)(smem + 16384);    // 8 KB
    ushort_t* sB1 = (ushort_t*)(smem + 24576);    // 8 KB
    float*    nb_s = (float*)(smem + 32768);      // 512 B

    const int tid  = threadIdx.x;
    const int lane = tid & 63;
    const int wave = tid >> 6;
    const int wm = wave >> 1, wn = wave & 1;
    // XCD-aware bijective swizzle: grid 32x32 = 1024 = 8*128
    const int flat = blockIdx.y * (HW / 128) + blockIdx.x;
    const int orig = (flat & 7) * 128 + (flat >> 3);
    const int bm = orig >> 5, bn = orig & 31;
    const int l15 = lane & 15, l4 = lane >> 4;
    const int swz = (l15 >> 1) & 3;

    floatx4 acc[4][4];
#pragma unroll
    for (int i = 0; i < 4; ++i)
#pragma unroll
        for (int j = 0; j < 4; ++j) acc[i][j] = (floatx4){0.f, 0.f, 0.f, 0.f};

    auto stage = [&](int kb, ushort_t* dA, ushort_t* dB) {
        const size_t aoff = (size_t)(kb * HW + bm * 128) * 32 + tid * 8;
        const size_t boff = (size_t)(kb * HW + bn * 128) * 32 + tid * 8;
        async_cp16(Ah + aoff,        dA + tid * 8);
        async_cp16(Ah + aoff + 2048, dA + tid * 8 + 2048);
        async_cp16(Bh + boff,        dB + tid * 8);
        async_cp16(Bh + boff + 2048, dB + tid * 8 + 2048);
    };
    auto compute = [&](const ushort_t* pA, const ushort_t* pB) {
        shortx8 af[4], bf_[4];
#pragma unroll
        for (int i = 0; i < 4; ++i)
            af[i] = *(const shortx8*)&pA[((wm * 4 + i) * 16 + l15) * 32 + ((l4 ^ swz) * 8)];
#pragma unroll
        for (int j = 0; j < 4; ++j)
            bf_[j] = *(const shortx8*)&pB[((wn * 4 + j) * 16 + l15) * 32 + ((l4 ^ swz) * 8)];
#pragma unroll
        for (int i = 0; i < 4; ++i)
#pragma unroll
            for (int j = 0; j < 4; ++j)
                acc[i][j] = __builtin_amdgcn_mfma_f32_16x16x32_bf16(af[i], bf_[j], acc[i][j], 0, 0, 0);
    };

    // prologue: stage kb=0 into buf0; its latency overlaps the nb_s work
    stage(0, sA0, sB0);
    if (tid < 128) {
        float s = 0.f;
        int q = bn * 128 + tid;
#pragma unroll
        for (int ch = 0; ch < NNB; ++ch) s += nbp2[ch * HW + q];
        nb_s[tid] = 1.0f / (sqrtf(s + EPS) + EPS);
    }
    __syncthreads();

    // main loop, manually unrolled x2 so buffer choice is compile-time
    for (int kb = 0; kb < NKB; kb += 2) {
        stage(kb + 1, sA1, sB1);          // kb+1 <= 23 always valid (NKB even)
        compute(sA0, sB0);
        __syncthreads();
        if (kb + 2 < NKB) stage(kb + 2, sA0, sB0);
        compute(sA1, sB1);
        __syncthreads();
    }

    float rnb[4];
#pragma unroll
    for (int j = 0; j < 4; ++j)
        rnb[j] = nb_s[wn * 64 + j * 16 + l15];

    float* lv1 = (float*)smem;
    int*   li1 = (int*)(smem + 1024);
    float* lv2 = (float*)(smem + 2048);
    int*   li2 = (int*)(smem + 3072);

#pragma unroll
    for (int i = 0; i < 4; ++i) {
#pragma unroll
        for (int r = 0; r < 4; ++r) {
            float v1 = -INFINITY, v2 = -INFINITY; int i1 = 0, i2 = 0;
#pragma unroll
            for (int j = 0; j < 4; ++j) {
                float sv = acc[i][j][r] * rnb[j];
                int q = bn * 128 + wn * 64 + j * 16 + l15;
                if (sv > v1) { v2 = v1; i2 = i1; v1 = sv; i1 = q; }
                else if (sv > v2) { v2 = sv; i2 = q; }
            }
#pragma unroll
            for (int m = 1; m < 16; m <<= 1) {
                float ov1 = __shfl_xor(v1, m, 64);
                int   oi1 = __shfl_xor(i1, m, 64);
                float ov2 = __shfl_xor(v2, m, 64);
                int   oi2 = __shfl_xor(i2, m, 64);
                if (ov1 > v1 || (ov1 == v1 && oi1 < i1)) {
                    if (v1 > ov2 || (v1 == ov2 && i1 < oi2)) { v2 = v1; i2 = i1; }
                    else { v2 = ov2; i2 = oi2; }
                    v1 = ov1; i1 = oi1;
                } else if (ov1 > v2 || (ov1 == v2 && oi1 < i2)) {
                    v2 = ov1; i2 = oi1;
                }
            }
            if (l15 == 0) {
                int pl = wm * 64 + i * 16 + l4 * 4 + r;
                lv1[pl * 2 + wn] = v1; li1[pl * 2 + wn] = i1;
                lv2[pl * 2 + wn] = v2; li2[pl * 2 + wn] = i2;
            }
        }
    }
    __syncthreads();
    if (tid < 128) {
        float v1 = lv1[tid * 2],     v2 = lv2[tid * 2];
        int   i1 = li1[tid * 2],     i2 = li2[tid * 2];
        float w1 = lv1[tid * 2 + 1], w2 = lv2[tid * 2 + 1];
        int   j1 = li1[tid * 2 + 1], j2 = li2[tid * 2 + 1];
        if (w1 > v1 || (w1 == v1 && j1 < i1)) {
            if (v1 > w2 || (v1 == w2 && i1 < j2)) { v2 = v1; i2 = i1; }
            else { v2 = w2; i2 = j2; }
            v1 = w1; i1 = j1;
        } else if (w1 > v2 || (w1 == v2 && j1 < i2)) {
            v2 = w1; i2 = j1;
        }
        int p = bm * 128 + tid;
        pv1[p * NBN + bn] = v1; pi1[p * NBN + bn] = i1;
        pv2[p * NBN + bn] = v2; pi2[p * NBN + bn] = i2;
    }

    // ---- transpose tail: 2-3 64x64 tiles per block (d->dT, b->bT, a->aT)
    __syncthreads();                       // epilogue LDS readers done
    {
        float (*tile)[65] = (float (*)[65])smem;     // 16640 B <= 33280
        const int r16 = tid >> 4;
        const int q4  = (tid & 15) * 4;
        const int flatb = blockIdx.y * (HW / 128) + blockIdx.x;  // 0..1023
        for (int tt = flatb; tt < NTT; tt += 1024) {
            const int which = tt / 768;              // 0=d, 1=b, 2=a
            const int idx = tt - which * 768;
            if (which == 2 && !at_ok) break;         // aT tiles are always last
            const float* src = (which == 0) ? d : ((which == 1) ? b : a);
            float*       dst = (which == 0) ? dT : ((which == 1) ? bT : aT);
            const int tp0 = (idx & 63) * 64;
            const int tc0 = (idx >> 6) * 64;
#pragma unroll
            for (int pp = 0; pp < 4; ++pp) {
                int c = pp * 16 + r16;
                float4 v = *(const float4*)&src[(size_t)(tc0 + c) * HW + tp0 + q4];
                tile[c][q4]     = v.x; tile[c][q4 + 1] = v.y;
                tile[c][q4 + 2] = v.z; tile[c][q4 + 3] = v.w;
            }
            __syncthreads();
#pragma unroll
            for (int pp = 0; pp < 4; ++pp) {
                int p = pp * 16 + r16;
                float4 v;
                v.x = tile[q4][p];     v.y = tile[q4 + 1][p];
                v.z = tile[q4 + 2][p]; v.w = tile[q4 + 3][p];
                *(float4*)&dst[(size_t)(tp0 + p) * C + tc0 + q4] = v;
            }
            __syncthreads();
        }
    }
}

// ---------------------------------------------------------------------------
// reduce+recheck: 4 rows per block (1 per wave). Top-2 merge over 32 tiles.
// Flagged rows: candidates within TAU of the global bf16 max are rechecked
// COOPERATIVELY -- all 64 lanes split each candidate's 768-dot. (R7-exact.)
// ---------------------------------------------------------------------------
__global__ __launch_bounds__(256) void reduce_recheck_kernel(
    const float* __restrict__ a, const float* __restrict__ b,
    const float* __restrict__ bT, int bt_ok,
    const float* __restrict__ aT, int at_ok,
    const float* __restrict__ pv1, const int* __restrict__ pi1,
    const float* __restrict__ pv2, const int* __restrict__ pi2,
    int* __restrict__ zb, float* __restrict__ out_zbest)
{
    const int wave = threadIdx.x >> 6, lane = threadIdx.x & 63;
    const int p = blockIdx.x * 4 + wave;
    const int tq = lane & 31;

    float v1, v2, candv; int i1, cand;
    if (lane < 32) {
        v1 = pv1[p * NBN + tq]; i1 = pi1[p * NBN + tq]; v2 = pv2[p * NBN + tq];
        cand = i1; candv = v1;
    } else {
        v1 = -INFINITY; v2 = -INFINITY; i1 = 0x7fffffff;
        cand = pi2[p * NBN + tq];
        candv = pv2[p * NBN + tq];
    }
#pragma unroll
    for (int m = 1; m < 32; m <<= 1) {
        float ov1 = __shfl_xor(v1, m, 64);
        int   oi1 = __shfl_xor(i1, m, 64);
        float ov2 = __shfl_xor(v2, m, 64);
        if (ov1 > v1 || (ov1 == v1 && oi1 < i1)) {
            v2 = fmaxf(v1, ov2); v1 = ov1; i1 = oi1;
        } else {
            v2 = fmaxf(v2, ov1);
        }
    }
    v1 = __shfl(v1, 0, 64); v2 = __shfl(v2, 0, 64); i1 = __shfl(i1, 0, 64);

    if (v1 - v2 >= TAU) {
        if (lane == 0) { zb[p] = i1; out_zbest[p] = (float)i1; }
        return;
    }

    const bool active = candv >= v1 - TAU;

    if (at_ok) {
        unsigned long long mset = __ballot(active);
        const float* ar = aT + (size_t)p * C + lane * 12;
        float4 a0 = *(const float4*)ar;
        float4 a1 = *(const float4*)(ar + 4);
        float4 a2v = *(const float4*)(ar + 8);
        float bests = -INFINITY; int bestq = 0x7fffffff;
        while (mset) {
            const int src = __ffsll(mset) - 1;
            mset &= mset - 1;
            const int qc = __shfl(cand, src, 64);
            const float* br = bT + (size_t)qc * C + lane * 12;
            float4 b0 = *(const float4*)br;
            float4 b1 = *(const float4*)(br + 4);
            float4 b2v = *(const float4*)(br + 8);
            float dot = a0.x * b0.x + a0.y * b0.y + a0.z * b0.z + a0.w * b0.w
                      + a1.x * b1.x + a1.y * b1.y + a1.z * b1.z + a1.w * b1.w
                      + a2v.x * b2v.x + a2v.y * b2v.y + a2v.z * b2v.z + a2v.w * b2v.w;
            float bb  = b0.x * b0.x + b0.y * b0.y + b0.z * b0.z + b0.w * b0.w
                      + b1.x * b1.x + b1.y * b1.y + b1.z * b1.z + b1.w * b1.w
                      + b2v.x * b2v.x + b2v.y * b2v.y + b2v.z * b2v.z + b2v.w * b2v.w;
#pragma unroll
            for (int m = 1; m < 64; m <<= 1) {
                dot += __shfl_xor(dot, m, 64);
                bb  += __shfl_xor(bb, m, 64);
            }
            const float s = dot / (sqrtf(bb + EPS) + EPS);
            if (s > bests || (s == bests && qc < bestq)) { bests = s; bestq = qc; }
        }
        if (lane == 0) { zb[p] = bestq; out_zbest[p] = (float)bestq; }
        return;
    }

    // fallback (no aT): per-lane recheck
    int q = cand;
    float dot = 0.f, b2 = 0.f;
    if (active) {
        if (bt_ok) {
            const float* br = bT + (size_t)q * C;
            const float* ap = a + p;
#pragma unroll 4
            for (int c = 0; c < C; c += 4) {
                float4 bv = *(const float4*)(br + c);
                dot += ap[(size_t)c * HW] * bv.x + ap[(size_t)(c + 1) * HW] * bv.y
                     + ap[(size_t)(c + 2) * HW] * bv.z + ap[(size_t)(c + 3) * HW] * bv.w;
                b2  += bv.x * bv.x + bv.y * bv.y + bv.z * bv.z + bv.w * bv.w;
            }
        } else {
#pragma unroll 8
            for (int c = 0; c < C; ++c) {
                float av = a[c * HW + p];
                float bv = b[c * HW + q];
                dot += av * bv; b2 += bv * bv;
            }
        }
    }
    float s = active ? (dot / (sqrtf(b2 + EPS) + EPS)) : -INFINITY;
#pragma unroll
    for (int m = 1; m < 64; m <<= 1) {
        float os = __shfl_xor(s, m, 64);
        int   oq = __shfl_xor(q, m, 64);
        if (os > s || (os == s && oq < q)) { s = os; q = oq; }
    }
    if (lane == 0) { zb[p] = q; out_zbest[p] = (float)q; }
}

// ---------------------------------------------------------------------------
// transpose-gather z_new + fused cos-loss partials. 32p x 64c tiles
// (grid 128x12 = 1536 blocks) -- the R7-proven latency-hiding config.
// ---------------------------------------------------------------------------
__global__ __launch_bounds__(256) void gather_loss_kernel(
    const float* __restrict__ a, const float* __restrict__ dT,
    const int* __restrict__ zb, float* __restrict__ out,
    float* __restrict__ pdot, float* __restrict__ pa2, float* __restrict__ pt2)
{
    __shared__ float tile[32][65];
    __shared__ int qs[32];
    const int t = threadIdx.x;
    const int p0 = blockIdx.x * 32;
    const int c0 = blockIdx.y * 64;
    if (t < 32) qs[t] = zb[p0 + t];
    __syncthreads();

    {
        const int pl = t >> 3, sub = t & 7;          // 32 rows x 8 threads
        const float* src = dT + (size_t)qs[pl] * C + c0 + sub * 8;
        float4 v0 = *(const float4*)(src);
        float4 v1 = *(const float4*)(src + 4);
        float* dst = &tile[pl][sub * 8];
        dst[0] = v0.x; dst[1] = v0.y; dst[2] = v0.z; dst[3] = v0.w;
        dst[4] = v1.x; dst[5] = v1.y; dst[6] = v1.z; dst[7] = v1.w;
    }
    __syncthreads();

    const int p = t & 31, cg = t >> 5;               // 8 groups x 8 c
    float dot = 0.f, a2 = 0.f, t2 = 0.f;
#pragma unroll
    for (int i = 0; i < 8; ++i) {
        int cc = cg * 8 + i;
        float tv = tile[p][cc];
        float av = a[(size_t)(c0 + cc) * HW + p0 + p];
        out[1 + (size_t)(c0 + cc) * HW + p0 + p] = tv;
        dot += av * tv; a2 += av * av; t2 += tv * tv;
    }
    __shared__ float r1[256], r2[256], r3[256];
    r1[t] = dot; r2[t] = a2; r3[t] = t2;
    __syncthreads();
    if (t < 32) {
        float fd = 0.f, fa = 0.f, ft = 0.f;
#pragma unroll
        for (int g = 0; g < 8; ++g) {
            fd += r1[t + g * 32];
            fa += r2[t + g * 32];
            ft += r3[t + g * 32];
        }
        pdot[blockIdx.y * HW + p0 + t] = fd;
        pa2[blockIdx.y * HW + p0 + t]  = fa;
        pt2[blockIdx.y * HW + p0 + t]  = ft;
    }
}

// loss finalize: float4 over p (4 p per thread), grid = HW/1024
__global__ __launch_bounds__(256) void loss_finalize_kernel(
    const float* __restrict__ pdot, const float* __restrict__ pa2,
    const float* __restrict__ pt2, float* __restrict__ out, int nch)
{
    int p4 = (blockIdx.x * 256 + threadIdx.x) * 4;
    float d0 = 0.f, d1 = 0.f, d2 = 0.f, d3 = 0.f;
    float a0 = 0.f, a1 = 0.f, a2 = 0.f, a3 = 0.f;
    float t0 = 0.f, t1 = 0.f, t2 = 0.f, t3 = 0.f;
    for (int ch = 0; ch < nch; ++ch) {
        float4 dv = *(const float4*)&pdot[(size_t)ch * HW + p4];
        float4 av = *(const float4*)&pa2[(size_t)ch * HW + p4];
        float4 tv = *(const float4*)&pt2[(size_t)ch * HW + p4];
        d0 += dv.x; d1 += dv.y; d2 += dv.z; d3 += dv.w;
        a0 += av.x; a1 += av.y; a2 += av.z; a3 += av.w;
        t0 += tv.x; t1 += tv.y; t2 += tv.z; t3 += tv.w;
    }
    float contrib =
        (1.f - d0 / ((sqrtf(a0) + EPS) * (sqrtf(t0) + EPS))) +
        (1.f - d1 / ((sqrtf(a1) + EPS) * (sqrtf(t1) + EPS))) +
        (1.f - d2 / ((sqrtf(a2) + EPS) * (sqrtf(t2) + EPS))) +
        (1.f - d3 / ((sqrtf(a3) + EPS) * (sqrtf(t3) + EPS)));
    __shared__ float red[256];
    red[threadIdx.x] = contrib;
    __syncthreads();
    for (int s = 128; s > 0; s >>= 1) {
        if (threadIdx.x < s) red[threadIdx.x] += red[threadIdx.x + s];
        __syncthreads();
    }
    if (threadIdx.x == 0) atomicAdd(out, red[0] * (1.0f / HW));
}

// ---------------------------------------------------------------------------
// fp32 fallback path (only if workspace is unexpectedly small)
// ---------------------------------------------------------------------------
__global__ __launch_bounds__(256) void bnorm_partial_fb_kernel(
    const float* __restrict__ b, float* __restrict__ nbp)
{
    int q = blockIdx.x * 256 + threadIdx.x;
    int c0 = blockIdx.y * 32;
    float s = 0.f;
#pragma unroll 8
    for (int c = c0; c < c0 + 32; ++c) { float v = b[c * HW + q]; s += v * v; }
    nbp[blockIdx.y * HW + q] = s;
}

__global__ __launch_bounds__(256) void bnorm_finalize_fb_kernel(
    const float* __restrict__ nbp, float* __restrict__ nb)
{
    int q = blockIdx.x * 256 + threadIdx.x;
    float s = 0.f;
#pragma unroll
    for (int ch = 0; ch < NKB; ++ch) s += nbp[ch * HW + q];
    nb[q] = sqrtf(s + EPS) + EPS;
}

__global__ __launch_bounds__(256) void gemm_argmax_fb_kernel(
    const float* __restrict__ A, const float* __restrict__ B,
    const float* __restrict__ nb,
    float* __restrict__ pval, int* __restrict__ pidx)
{
    __shared__ __align__(16) char smem[16384];
    float (*As)[128] = (float (*)[128])smem;
    float (*Bs)[128] = (float (*)[128])(smem + 4096);
    const int m0 = blockIdx.x * 128, q0 = blockIdx.y * 128;
    const int tid = threadIdx.x;
    const int tx = tid & 15, ty = tid >> 4;
    const int lr = tid >> 5, lc = (tid & 31) * 4;
    float acc[8][8] = {};
    for (int k0 = 0; k0 < C; k0 += 8) {
        *(float4*)&As[lr][lc] = *(const float4*)&A[(k0 + lr) * HW + m0 + lc];
        *(float4*)&Bs[lr][lc] = *(const float4*)&B[(k0 + lr) * HW + q0 + lc];
        __syncthreads();
#pragma unroll
        for (int kk = 0; kk < 8; ++kk) {
            float a8[8], b8[8];
            *(float4*)&a8[0] = *(float4*)&As[kk][ty * 8];
            *(float4*)&a8[4] = *(float4*)&As[kk][ty * 8 + 4];
            *(float4*)&b8[0] = *(float4*)&Bs[kk][tx * 8];
            *(float4*)&b8[4] = *(float4*)&Bs[kk][tx * 8 + 4];
#pragma unroll
            for (int i = 0; i < 8; ++i)
#pragma unroll
                for (int j = 0; j < 8; ++j) acc[i][j] += a8[i] * b8[j];
        }
        __syncthreads();
    }
    float nbv[8];
#pragma unroll
    for (int j = 0; j < 8; ++j) nbv[j] = nb[q0 + tx * 8 + j];
    float (*rv)[16] = (float (*)[16])smem;
    int   (*ri)[16] = (int   (*)[16])(smem + 8192);
#pragma unroll
    for (int i = 0; i < 8; ++i) {
        float bv = -INFINITY; int bi = 0;
#pragma unroll
        for (int j = 0; j < 8; ++j) {
            float s = acc[i][j] / nbv[j];
            int q = q0 + tx * 8 + j;
            if (s > bv) { bv = s; bi = q; }
        }
        rv[ty * 8 + i][tx] = bv;
        ri[ty * 8 + i][tx] = bi;
    }
    __syncthreads();
    if (tid < 128) {
        float bv = rv[tid][0]; int bi = ri[tid][0];
#pragma unroll
        for (int t = 1; t < 16; ++t) {
            float v = rv[tid][t]; int ii = ri[tid][t];
            if (v > bv || (v == bv && ii < bi)) { bv = v; bi = ii; }
        }
        pval[(m0 + tid) * NBN + blockIdx.y] = bv;
        pidx[(m0 + tid) * NBN + blockIdx.y] = bi;
    }
}

__global__ __launch_bounds__(256) void reduce_fb_kernel(
    const float* __restrict__ pval, const int* __restrict__ pidx,
    int* __restrict__ zb, float* __restrict__ out_zbest)
{
    int p = blockIdx.x * 256 + threadIdx.x;
    float bv = pval[p * NBN]; int bi = pidx[p * NBN];
#pragma unroll 8
    for (int t = 1; t < NBN; ++t) {
        float v = pval[p * NBN + t]; int ii = pidx[p * NBN + t];
        if (v > bv || (v == bv && ii < bi)) { bv = v; bi = ii; }
    }
    zb[p] = bi;
    out_zbest[p] = (float)bi;
}

__global__ __launch_bounds__(256) void gather_partial_kernel(
    const float* __restrict__ a, const float* __restrict__ d,
    const int* __restrict__ zb, float* __restrict__ out,
    float* __restrict__ pdot, float* __restrict__ pa2, float* __restrict__ pt2)
{
    int p = blockIdx.x * 256 + threadIdx.x;
    int ch = blockIdx.y;
    int c0 = ch * (C / NCH_OLD);
    int q = zb[p];
    float dot = 0.f, a2 = 0.f, t2 = 0.f;
#pragma unroll
    for (int c = c0; c < c0 + C / NCH_OLD; ++c) {
        float av = a[c * HW + p];
        float tv = d[c * HW + q];
        dot += av * tv; a2 += av * av; t2 += tv * tv;
        out[1 + c * HW + p] = tv;
    }
    pdot[ch * HW + p] = dot;
    pa2[ch * HW + p] = a2;
    pt2[ch * HW + p] = t2;
}

extern "C" void kernel_launch(void* const* d_in, const int* in_sizes, int n_in,
                              void* d_out, int out_size, void* d_ws, size_t ws_size,
                              hipStream_t stream) {
    const float* a = (const float*)d_in[0];
    const float* b = (const float*)d_in[1];
    const float* d = (const float*)d_in[2];
    float* out = (float*)d_out;
    float* out_zbest = out + 1 + (size_t)C * HW;

    char* ws = (char*)d_ws;
    size_t off = 0;
    auto alloc = [&](size_t bytes) { void* p = ws + off; off = (off + bytes + 255) & ~(size_t)255; return p; };

    const size_t PACK = (size_t)C * HW * 2;  // 6.29 MB
    ushort_t* Ah = (ushort_t*)alloc(PACK);
    ushort_t* Bh = (ushort_t*)alloc(PACK);
    float* nbp = (float*)alloc((size_t)NKB * HW * 4);
    float* pv1 = (float*)alloc((size_t)HW * NBN * 4);
    int*   pi1 = (int*)alloc((size_t)HW * NBN * 4);
    float* pv2 = (float*)alloc((size_t)HW * NBN * 4);
    int*   pi2 = (int*)alloc((size_t)HW * NBN * 4);
    int*   zb  = (int*)alloc(HW * 4);
    float* pdot = (float*)alloc((size_t)NCH_NEW * HW * 4);
    float* pa2  = (float*)alloc((size_t)NCH_NEW * HW * 4);
    float* pt2  = (float*)alloc((size_t)NCH_NEW * HW * 4);
    float* dT  = (float*)alloc((size_t)C * HW * 4);   // 12.6 MB
    float* bT  = (float*)alloc((size_t)C * HW * 4);   // 12.6 MB
    bool fast = off <= ws_size;                       // ~41 MB
    float* aT  = (float*)alloc((size_t)C * HW * 4);   // 12.6 MB (optional)
    int at_ok = (off <= ws_size) ? 1 : 0;             // ~54 MB

    if (fast) {
        prep_kernel<<<dim3(HW / 64, C / 64), 256, 0, stream>>>(
            a, b, Ah, Bh, nbp, out);
        gemm_mfma_kernel<<<dim3(HW / 128, HW / 128), 256, 0, stream>>>(
            Ah, Bh, nbp, a, b, d, dT, bT, aT, at_ok, pv1, pi1, pv2, pi2);
        reduce_recheck_kernel<<<HW / 4, 256, 0, stream>>>(
            a, b, bT, 1, aT, at_ok, pv1, pi1, pv2, pi2, zb, out_zbest);
        gather_loss_kernel<<<dim3(HW / 32, NCH_NEW), 256, 0, stream>>>(
            a, dT, zb, out, pdot, pa2, pt2);
        loss_finalize_kernel<<<HW / 1024, 256, 0, stream>>>(pdot, pa2, pt2, out, NCH_NEW);
    } else {
        // compact fp32 fallback
        off = 0;
        float* nb = (float*)alloc(HW * 4);
        nbp = (float*)alloc((size_t)NKB * HW * 4);
        pv1 = (float*)alloc((size_t)HW * NBN * 4);
        pi1 = (int*)alloc((size_t)HW * NBN * 4);
        zb  = (int*)alloc(HW * 4);
        float* pdot2 = (float*)alloc((size_t)NCH_OLD * HW * 4);
        float* pa22  = (float*)alloc((size_t)NCH_OLD * HW * 4);
        float* pt22  = (float*)alloc((size_t)NCH_OLD * HW * 4);
        hipMemsetAsync(d_out, 0, sizeof(float), stream);
        bnorm_partial_fb_kernel<<<dim3(HW / 256, NKB), 256, 0, stream>>>(b, nbp);
        bnorm_finalize_fb_kernel<<<HW / 256, 256, 0, stream>>>(nbp, nb);
        gemm_argmax_fb_kernel<<<dim3(HW / 128, HW / 128), 256, 0, stream>>>(a, b, nb, pv1, pi1);
        reduce_fb_kernel<<<HW / 256, 256, 0, stream>>>(pv1, pi1, zb, out_zbest);
        gather_partial_kernel<<<dim3(HW / 256, NCH_OLD), 256, 0, stream>>>(
            a, d, zb, out, pdot2, pa22, pt22);
        loss_finalize_kernel<<<HW / 1024, 256, 0, stream>>>(pdot2, pa22, pt22, out, NCH_OLD);
    }
}